// Round 4
// baseline (936.262 us; speedup 1.0000x reference)
//
#include <hip/hip_runtime.h>
#include <hip/hip_fp16.h>
#include <math.h>

// Problem constants
#define BN 4
#define CC 31
#define HH 512
#define WW 512
#define HWSZ 262144  // 512*512

// Workspace: z2 field (b,c,h,w) fp16, then float stats region.
static const size_t Z2F = (size_t)BN * CC * HWSZ;
#define T_OFF   0
#define SSQ_OFF 124
#define R0_OFF  248
#define RL_OFF  372
#define C0_OFF  496
#define CL_OFF  620
#define COR_OFF 744
#define M2_OFF  1240
#define VB2_OFF 5208

typedef short v8s __attribute__((ext_vector_type(8)));   // 8 bf16 (A/B frag)
typedef float v4f __attribute__((ext_vector_type(4)));   // 4 f32  (C/D frag)
typedef _Float16 v4h __attribute__((ext_vector_type(4))); // 4 f16 (K=16 frag)

__device__ __forceinline__ short f2bf(float f) {   // f32 -> bf16 (RNE)
    unsigned u = __float_as_uint(f);
    return (short)((u + 0x7FFFu + ((u >> 16) & 1u)) >> 16);
}

// XCD-aware swizzle: each XCD gets a contiguous 512-tile region.
__device__ __forceinline__ void swizzle_tile(int& b, int& ty0, int& tx0) {
    const int lid = blockIdx.x + 32 * blockIdx.y + 1024 * blockIdx.z;
    const int vid = ((lid & 7) << 9) + (lid >> 3);
    b = vid >> 10;
    const int rem = vid & 1023;
    ty0 = (rem >> 5) << 4;
    tx0 = (rem & 31) << 4;
}

// ---------------------------------------------------------------------------
// Kernel A: 16x16 tile, 4 blocks/CU (LDS 40576 B).
// Four 16-channel passes (T0,T1,G0,G1); per pass:
//   wbuild: 1x1 weights [16][32] bf16 -> Wp
//   mfma:   field[px][16ch] f16 (XOR half-swizzle, bank-conflict-free)
//   dw3:    16 ch per thread; T passes -> Zb + edge stats; G -> z2out global
//   stats (T only): sum/ssq MFMA on Zb, wave-pair ks split, atomic merge.
// ---------------------------------------------------------------------------
__global__ __launch_bounds__(256, 4) void blockNL_k_stage1(
    const float* __restrict__ z,
    const float* __restrict__ nz_w, const float* __restrict__ nz_b,
    const float* __restrict__ t1w, const float* __restrict__ t1b,
    const float* __restrict__ t2w, const float* __restrict__ t2b,
    const float* __restrict__ g1w, const float* __restrict__ g1b,
    const float* __restrict__ g2w, const float* __restrict__ g2b,
    __half* __restrict__ z2out, float* __restrict__ stats)
{
    __shared__ __align__(16) short Vb[324 * 32];   // LN halo, bf16 [px][32ch] 20736 B
    __shared__ __align__(16) short Wp[16 * 32];    // per-pass 1x1 W bf16      1024 B
    __shared__ __align__(16) short Ff[324 * 16];   // per-pass field f16      10368 B
    __shared__ __align__(16) short Zb[16 * 264];   // per-pass z1 bf16 stats   8448 B

    const int tid = threadIdx.x;
    int b, ty0, tx0;
    swizzle_tile(b, ty0, tx0);

    const int w = tid >> 6, lane = tid & 63, quad = lane >> 4, m15 = lane & 15;
    const int ty = tid >> 4, tx = tid & 15;
    const int gy = ty0 + ty, gx = tx0 + tx;

    // ---- phase 1: stage LN field (bf16) into Vb ----
    for (int hp = tid; hp < 324; hp += 256) {
        const int hy = hp / 18, hx = hp - hy * 18;
        const int zy = ty0 + hy - 1, zx = tx0 + hx - 1;
        const bool valid = ((unsigned)zy < (unsigned)HH) && ((unsigned)zx < (unsigned)WW);
        int pk[16];
        if (valid) {
            const float* zp = z + (size_t)b * CC * HWSZ + (size_t)zy * WW + zx;
            float v[CC];
            float mu = 0.f;
            #pragma unroll
            for (int c = 0; c < CC; ++c) { v[c] = zp[(size_t)c * HWSZ]; mu += v[c]; }
            mu *= (1.f / 31.f);
            float var = 0.f;
            #pragma unroll
            for (int c = 0; c < CC; ++c) { float d = v[c] - mu; v[c] = d; var += d * d; }
            var *= (1.f / 31.f);
            const float rs = rsqrtf(var + 1e-5f);
            #pragma unroll
            for (int c = 0; c < CC; ++c) v[c] = v[c] * rs * nz_w[c] + nz_b[c];
            #pragma unroll
            for (int i = 0; i < 16; ++i) {
                const unsigned lo = (unsigned short)f2bf(v[2 * i]);
                const unsigned hi = (2 * i + 1 < CC) ? (unsigned short)f2bf(v[2 * i + 1]) : 0u;
                pk[i] = (int)(lo | (hi << 16));
            }
        } else {
            #pragma unroll
            for (int i = 0; i < 16; ++i) pk[i] = 0;
        }
        int* dst = (int*)&Vb[hp * 32];
        #pragma unroll
        for (int q = 0; q < 4; ++q) {
            int4 t; t.x = pk[q*4]; t.y = pk[q*4+1]; t.z = pk[q*4+2]; t.w = pk[q*4+3];
            ((int4*)dst)[q] = t;
        }
    }

    // per-pass 1x1 weight tile: rows ct*16..ct*16+15 of t1w (p<2) or g1w
    auto wbuild = [&](int p) {
        const float* W1 = (p >= 2) ? g1w : t1w;
        const int ct = p & 1;
        const int m = tid >> 4, kp = tid & 15;
        const int gr = ct * 16 + m;
        const int k0 = 2 * kp, k1 = k0 + 1;
        float w0 = 0.f, w1 = 0.f;
        if (gr < CC) {
            if (k0 < CC) w0 = W1[gr * CC + k0];
            if (k1 < CC) w1 = W1[gr * CC + k1];
        }
        ((int*)Wp)[m * 16 + kp] =
            (int)((unsigned short)f2bf(w0) | ((unsigned)(unsigned short)f2bf(w1) << 16));
    };

    // MFMA matvec: field[px][16] f16; half-index XOR swizzle keyed on px bit 2
    auto mfma_pass = [&](int p) {
        const int ct = p & 1;
        const float* B1 = (p >= 2) ? g1b : t1b;
        const v8s afrag = *(const v8s*)&Wp[m15 * 32 + quad * 8];
        float bias[4];
        #pragma unroll
        for (int r = 0; r < 4; ++r) {
            const int row = ct * 16 + quad * 4 + r;
            bias[r] = (row < CC) ? B1[row] : 0.f;
        }
        for (int j = w; j < 21; j += 4) {
            const int px = j * 16 + m15;
            const int pc = (px < 324) ? px : 323;   // clamp tail (garbage, unstored)
            const v8s bfrag = *(const v8s*)&Vb[pc * 32 + quad * 8];
            v4f acc = {0.f, 0.f, 0.f, 0.f};
            acc = __builtin_amdgcn_mfma_f32_16x16x32_bf16(afrag, bfrag, acc, 0, 0, 0);
            if (px < 324) {
                unsigned d0 = (unsigned)__half_as_ushort(__float2half(acc[0] + bias[0]))
                            | ((unsigned)__half_as_ushort(__float2half(acc[1] + bias[1])) << 16);
                unsigned d1 = (unsigned)__half_as_ushort(__float2half(acc[2] + bias[2]))
                            | ((unsigned)__half_as_ushort(__float2half(acc[3] + bias[3])) << 16);
                const int half = (quad >> 1) ^ ((px >> 2) & 1);
                int2 st; st.x = (int)d0; st.y = (int)d1;
                *(int2*)&Ff[px * 16 + half * 8 + (quad & 1) * 4] = st;
            }
        }
    };

    auto dw3_pass = [&](int p) {
        const int ct = p & 1;
        const bool isG = (p >= 2);
        const float* W3 = isG ? g2w : t2w;
        const float* B3 = isG ? g2b : t2b;
        float s[16];
        #pragma unroll
        for (int r = 0; r < 16; ++r) {
            const int ch = ct * 16 + r;
            s[r] = (ch < CC) ? B3[ch] : 0.f;
        }
        #pragma unroll
        for (int dy = 0; dy < 3; ++dy)
            #pragma unroll
            for (int dx = 0; dx < 3; ++dx) {
                const int hp = (ty + dy) * 18 + (tx + dx);
                const int sel = (hp >> 2) & 1;
                const v8s f0 = *(const v8s*)&Ff[hp * 16 + sel * 8];        // ch 0-7
                const v8s f1 = *(const v8s*)&Ff[hp * 16 + (sel ^ 1) * 8];  // ch 8-15
                #pragma unroll
                for (int r = 0; r < 16; ++r) {
                    const int ch = ct * 16 + r;
                    const float wv = (ch < CC) ? W3[ch * 9 + dy * 3 + dx] : 0.f;
                    const float fv = __half2float(__ushort_as_half(
                        (unsigned short)((r < 8) ? f0[r] : f1[r - 8])));
                    s[r] += wv * fv;
                }
            }
        if (isG) {
            const size_t zbase = (size_t)b * CC * HWSZ + (size_t)gy * WW + gx;
            #pragma unroll
            for (int r = 0; r < 16; ++r) {
                const int ch = ct * 16 + r;
                if (ch < CC) z2out[zbase + (size_t)ch * HWSZ] = __float2half(s[r]);
            }
        } else {
            const bool top = (gy == 0), bot = (gy == HH - 1);
            const bool lef = (gx == 0), rig = (gx == WW - 1);
            #pragma unroll
            for (int r = 0; r < 16; ++r) {
                const int ch = ct * 16 + r;
                if (ch < CC) {
                    Zb[r * 264 + tid] = f2bf(s[r]);
                    if (top) atomicAdd(&stats[R0_OFF + b * CC + ch], s[r]);
                    if (bot) atomicAdd(&stats[RL_OFF + b * CC + ch], s[r]);
                    if (lef) atomicAdd(&stats[C0_OFF + b * CC + ch], s[r]);
                    if (rig) atomicAdd(&stats[CL_OFF + b * CC + ch], s[r]);
                    if ((top || bot) && (lef || rig))
                        stats[COR_OFF + (b * CC + ch) * 4 + (bot ? 2 : 0) + (rig ? 1 : 0)] = s[r];
                } else {
                    Zb[r * 264 + tid] = 0;   // clean pad row
                }
            }
        }
    };

    // stats: waves 0,1 = sums (ks halves), waves 2,3 = ssq (ks halves)
    auto stats_pass = [&](int ct) {
        const bool dosq = (w >> 1);
        const int kh = w & 1;
        v8s ones;
        #pragma unroll
        for (int i = 0; i < 8; ++i) ones[i] = (short)0x3F80;
        v4f acc = {0.f, 0.f, 0.f, 0.f};
        #pragma unroll
        for (int i = 0; i < 4; ++i) {
            const int ks = kh * 4 + i;
            const v8s bf = *(const v8s*)&Zb[m15 * 264 + ks * 32 + quad * 8];
            acc = __builtin_amdgcn_mfma_f32_16x16x32_bf16(dosq ? bf : ones, bf, acc, 0, 0, 0);
        }
        if (!dosq) {
            if (quad == 0) {
                const int ch = ct * 16 + m15;
                if (ch < CC) atomicAdd(&stats[T_OFF + b * CC + ch], acc[0]);
            }
        } else {
            if ((m15 >> 2) == quad) {   // diagonal lane for n = m15
                const int r = m15 & 3;
                const int ch = ct * 16 + m15;
                if (ch < CC) atomicAdd(&stats[SSQ_OFF + b * CC + ch], acc[r]);
            }
        }
    };

    wbuild(0);
    __syncthreads();
    mfma_pass(0);
    __syncthreads();
    dw3_pass(0);
    __syncthreads();
    stats_pass(0); wbuild(1);
    __syncthreads();
    mfma_pass(1);
    __syncthreads();
    dw3_pass(1);
    __syncthreads();
    stats_pass(1); wbuild(2);
    __syncthreads();
    mfma_pass(2);
    __syncthreads();
    dw3_pass(2); wbuild(3);
    __syncthreads();
    mfma_pass(3);
    __syncthreads();
    dw3_pass(3);
}

// ---------------------------------------------------------------------------
// Kernel B (4 blocks, one per batch): analytic x1, attention, fold M2/vb2.
// ---------------------------------------------------------------------------
__global__ void blockNL_k_att(
    const float* __restrict__ nx_b,
    const float* __restrict__ p1w, const float* __restrict__ p1b,
    const float* __restrict__ p2w, const float* __restrict__ p2b,
    const float* __restrict__ ww,  const float* __restrict__ wb,
    const float* __restrict__ vw,  const float* __restrict__ vb,
    float* stats)
{
    __shared__ float x1v[CC][9];
    __shared__ float dxs[CC];
    __shared__ float att[CC][CC];
    __shared__ float WA[CC][CC];

    const int tid = threadIdx.x;
    const int b = blockIdx.x;
    const float cnt[9] = {1.f, 510.f, 1.f, 510.f, 260100.f, 510.f, 1.f, 510.f, 1.f};

    if (tid < CC) {
        const float a = nx_b[0];
        const float u = p1w[tid] * a + p1b[tid];
        float w9[9];
        #pragma unroll
        for (int k = 0; k < 9; ++k) w9[k] = p2w[tid * 9 + k];
        float ssq = 0.f;
        #pragma unroll
        for (int ry = 0; ry < 3; ++ry) {
            #pragma unroll
            for (int rx = 0; rx < 3; ++rx) {
                float wsum = 0.f;
                #pragma unroll
                for (int ky = 0; ky < 3; ++ky) {
                    #pragma unroll
                    for (int kx = 0; kx < 3; ++kx) {
                        const bool okr = (ry == 1) || (ry == 0 && ky >= 1) || (ry == 2 && ky <= 1);
                        const bool okc = (rx == 1) || (rx == 0 && kx >= 1) || (rx == 2 && kx <= 1);
                        if (okr && okc) wsum += w9[ky * 3 + kx];
                    }
                }
                const float val = u * wsum + p2b[tid];
                x1v[tid][ry * 3 + rx] = val;
                ssq += cnt[ry * 3 + rx] * val * val;
            }
        }
        dxs[tid] = fmaxf(sqrtf(ssq), 1e-12f);
    }
    if (b == 0 && tid < 32) {
        float s = vb[tid];
        #pragma unroll
        for (int c = 0; c < CC; ++c) s += vw[tid * 32 + c + 1] * wb[c];
        stats[VB2_OFF + tid] = s;
    }
    __syncthreads();

    if (tid < CC) {
        const int c = tid;
        const float Tt  = stats[T_OFF  + b * CC + c];
        const float sq  = stats[SSQ_OFF + b * CC + c];
        const float r0  = stats[R0_OFF + b * CC + c];
        const float rL  = stats[RL_OFF + b * CC + c];
        const float c0  = stats[C0_OFF + b * CC + c];
        const float cL  = stats[CL_OFF + b * CC + c];
        const float k00 = stats[COR_OFF + (b * CC + c) * 4 + 0];
        const float k01 = stats[COR_OFF + (b * CC + c) * 4 + 1];
        const float k10 = stats[COR_OFF + (b * CC + c) * 4 + 2];
        const float k11 = stats[COR_OFF + (b * CC + c) * 4 + 3];
        float T[9];
        T[0] = k00; T[2] = k01; T[6] = k10; T[8] = k11;
        T[1] = r0 - k00 - k01;
        T[7] = rL - k10 - k11;
        T[3] = c0 - k00 - k10;
        T[5] = cL - k01 - k11;
        T[4] = Tt - r0 - rL - c0 - cL + k00 + k01 + k10 + k11;
        const float dz = fmaxf(sqrtf(sq), 1e-12f);

        float Arow[CC];
        float mx = -3.4e38f;
        #pragma unroll
        for (int d = 0; d < CC; ++d) {
            float s = 0.f;
            #pragma unroll
            for (int r = 0; r < 9; ++r) s += T[r] * x1v[d][r];
            s = s / (dz * dxs[d]);
            Arow[d] = s;
            mx = fmaxf(mx, s);
        }
        float den = 0.f;
        #pragma unroll
        for (int d = 0; d < CC; ++d) { float e = expf(Arow[d] - mx); Arow[d] = e; den += e; }
        const float inv = 1.f / den;
        #pragma unroll
        for (int d = 0; d < CC; ++d) att[c][d] = Arow[d] * inv;
    }
    __syncthreads();
    if (tid < CC) {
        const int c2 = tid;
        #pragma unroll
        for (int d = 0; d < CC; ++d) {
            float s = 0.f;
            #pragma unroll
            for (int c = 0; c < CC; ++c) s += ww[c2 * CC + c] * att[c][d];
            WA[c2][d] = s;
        }
    }
    __syncthreads();
    if (tid < 32) {
        const int e = tid;
        #pragma unroll
        for (int d = 0; d < CC; ++d) {
            float s = 0.f;
            #pragma unroll
            for (int c2 = 0; c2 < CC; ++c2) s += vw[e * 32 + c2 + 1] * WA[c2][d];
            stats[M2_OFF + (b * 32 + e) * CC + d] = s;
        }
    }
}

// ---------------------------------------------------------------------------
// Kernel C: 16x16 tile. Per 8-ch chunk: z2 (halo2, RAW fp16 LDS), q=gelu(dw3)
// (fp16 LDS), pos=dw3(q); per-chunk U[256 px][16] fp16 = [pos+z(8) ; z2(8)],
// accumulate epilogue GEMM with K=16 fp16 MFMA per chunk (acc in VGPRs).
// LDS: 6400(zbh) + 5184(qbh) + 10240(Ub) + 1024(A2c) = 22848 B -> 7 blocks/CU
// (zbh/qbh fp16 costs nothing: z2 is fp16 in global, U is fp16 for the MFMA).
// A2c is rebuilt per chunk in the U-build phase (prev MFMA 2 barriers back).
// ---------------------------------------------------------------------------
__global__ __launch_bounds__(256, 7) void blockNL_k_out(
    const float* __restrict__ x, const float* __restrict__ z,
    const float* __restrict__ vw,
    const float* __restrict__ pe1w, const float* __restrict__ pe2w,
    const __half* __restrict__ z2, const float* __restrict__ stats,
    float* __restrict__ out)
{
    __shared__ __align__(16) short zbh[8][400];     // 20x20 z2 chunk, raw fp16
    __shared__ __align__(16) short qbh[8][324];     // 18x18 gelu chunk, fp16
    __shared__ __align__(16) short Ub[256 * 20];    // per-chunk U [px][16+pad] f16
    __shared__ __align__(16) short A2c[32 * 16];    // per-chunk A [e][16] f16

    const int tid = threadIdx.x;
    int b, ty0, tx0;
    swizzle_tile(b, ty0, tx0);
    const int ty = tid >> 4, tx = tid & 15;
    const int gy = ty0 + ty, gx = tx0 + tx;

    const float* M2 = stats + M2_OFF + b * 32 * CC;

    const int w = tid >> 6, lane = tid & 63, quad = lane >> 4, m15 = lane & 15;
    const int mt = w & 1, jbase = (w >> 1) * 8;
    const size_t zpix = (size_t)b * CC * HWSZ + (size_t)gy * WW + gx;

    v4f acc[8];
    #pragma unroll
    for (int jj = 0; jj < 8; ++jj) acc[jj] = (v4f){0.f, 0.f, 0.f, 0.f};

    // stage z2 chunk ci into zbh (raw fp16; zero outside / pad channel)
    auto stage = [&](int ci) {
        for (int idx = tid; idx < 3200; idx += 256) {
            const int c8 = idx / 400, p = idx - c8 * 400;
            const int ch = ci * 8 + c8;
            const int hy = p / 20, hx = p - hy * 20;
            const int zy = ty0 + hy - 2, zx = tx0 + hx - 2;
            unsigned short v = 0;
            if (ch < 31 && (unsigned)zy < (unsigned)HH && (unsigned)zx < (unsigned)WW)
                v = __half_as_ushort(z2[((size_t)(b * CC + ch)) * HWSZ + (size_t)zy * WW + zx]);
            zbh[c8][p] = (short)v;
        }
    };

    stage(0);

    for (int ci = 0; ci < 4; ++ci) {
        __syncthreads();   // zbh(ci) staged
        // q = gelu(dw3(z2, pe1)) on 18x18 halo-1 -> qbh fp16
        for (int idx = tid; idx < 2592; idx += 256) {
            const int c8 = idx / 324, p = idx - c8 * 324;
            const int ch = ci * 8 + c8;
            const int hy = p / 18, hx = p - hy * 18;
            const int qy = ty0 + hy - 1, qx = tx0 + hx - 1;
            float q = 0.f;
            if ((unsigned)qy < (unsigned)HH && (unsigned)qx < (unsigned)WW) {
                float s = 0.f;
                #pragma unroll
                for (int dy = 0; dy < 3; ++dy)
                    #pragma unroll
                    for (int dx = 0; dx < 3; ++dx) {
                        const float wv = (ch < 31) ? pe1w[ch * 9 + dy * 3 + dx] : 0.f;
                        s += wv * __half2float(__ushort_as_half(
                                 (unsigned short)zbh[c8][(hy + dy) * 20 + hx + dx]));
                    }
                q = 0.5f * s * (1.f + erff(s * 0.70710678118654752f));
            }
            qbh[c8][p] = (short)__half_as_ushort(__float2half(q));
        }
        __syncthreads();
        // A2c chunk build: k<8 -> vv[e][ci*8+k]; k>=8 -> M2[e][ci*8+k-8]
        // (prev MFMA's A2c reads finished 2 barriers ago; next read after barrier)
        for (int idx = tid; idx < 512; idx += 256) {
            const int e = idx >> 4, k = idx & 15;
            const int ch = ci * 8 + (k & 7);
            float v = 0.f;
            if (ch < 31) v = (k < 8) ? vw[e * 32 + 1 + ch] : M2[e * CC + ch];
            A2c[e * 16 + k] = (short)__half_as_ushort(__float2half(v));
        }
        // pos = dw3(q, pe2); per-chunk U row (fp16): [pos+z | z2-center(raw)]
        {
            unsigned pk[8];
            #pragma unroll
            for (int r = 0; r < 8; ++r) {
                const int ch = ci * 8 + r;
                float tval = 0.f;
                unsigned zvh = 0;
                if (ch < 31) {
                    float pos = 0.f;
                    #pragma unroll
                    for (int dy = 0; dy < 3; ++dy)
                        #pragma unroll
                        for (int dx = 0; dx < 3; ++dx)
                            pos += pe2w[ch * 9 + dy * 3 + dx] *
                                   __half2float(__ushort_as_half(
                                       (unsigned short)qbh[r][(ty + dy) * 18 + (tx + dx)]));
                    tval = pos + z[zpix + (size_t)ch * HWSZ];
                    zvh = (unsigned)(unsigned short)zbh[r][(ty + 2) * 20 + (tx + 2)];
                }
                pk[r] = (unsigned)__half_as_ushort(__float2half(tval)) | (zvh << 16);
            }
            // interleave: cols 0-7 = tval (pk low), cols 8-15 = zval (pk high)
            int* ub = (int*)&Ub[tid * 20];
            int2 s0, s1, s2, s3;
            s0.x = (int)((pk[0] & 0xFFFFu) | (pk[1] << 16));
            s0.y = (int)((pk[2] & 0xFFFFu) | (pk[3] << 16));
            s1.x = (int)((pk[4] & 0xFFFFu) | (pk[5] << 16));
            s1.y = (int)((pk[6] & 0xFFFFu) | (pk[7] << 16));
            s2.x = (int)((pk[0] >> 16) | (pk[1] & 0xFFFF0000u));
            s2.y = (int)((pk[2] >> 16) | (pk[3] & 0xFFFF0000u));
            s3.x = (int)((pk[4] >> 16) | (pk[5] & 0xFFFF0000u));
            s3.y = (int)((pk[6] >> 16) | (pk[7] & 0xFFFF0000u));
            ((int2*)ub)[0] = s0;
            ((int2*)ub)[1] = s1;
            ((int2*)ub)[2] = s2;
            ((int2*)ub)[3] = s3;
        }
        __syncthreads();   // Ub + A2c ready; zbh consumed -> restage under MFMA
        // partial epilogue GEMM: acc += A2c @ U(ci)   (K=16 fp16 MFMA)
        {
            const v4h a = *(const v4h*)&A2c[(mt * 16 + m15) * 16 + quad * 4];
            #pragma unroll
            for (int jj = 0; jj < 8; ++jj) {
                const int p = (jbase + jj) * 16 + m15;
                const v4h bv = *(const v4h*)&Ub[p * 20 + quad * 4];
                acc[jj] = __builtin_amdgcn_mfma_f32_16x16x16f16(a, bv, acc[jj], 0, 0, 0);
            }
        }
        if (ci < 3) stage(ci + 1);
    }

    // ---- epilogue: out = acc + vb2 + vw0*x ----
    {
        float vb2r[4], vw0[4];
        #pragma unroll
        for (int r = 0; r < 4; ++r) {
            const int e = mt * 16 + quad * 4 + r;
            vb2r[r] = stats[VB2_OFF + e];
            vw0[r]  = vw[e * 32];
        }
        #pragma unroll
        for (int jj = 0; jj < 8; ++jj) {
            const int p = (jbase + jj) * 16 + m15;
            const int py = p >> 4, px = p & 15;
            const int ogy = ty0 + py, ogx = tx0 + px;
            const float xv = x[(size_t)b * HWSZ + (size_t)ogy * WW + ogx];
            const size_t obase = (size_t)b * 32 * HWSZ + (size_t)ogy * WW + ogx;
            #pragma unroll
            for (int r = 0; r < 4; ++r) {
                const int e = mt * 16 + quad * 4 + r;
                out[obase + (size_t)e * HWSZ] = acc[jj][r] + vb2r[r] + vw0[r] * xv;
            }
        }
    }
}

// ---------------------------------------------------------------------------
extern "C" void kernel_launch(void* const* d_in, const int* in_sizes, int n_in,
                              void* d_out, int out_size, void* d_ws, size_t ws_size,
                              hipStream_t stream)
{
    (void)in_sizes; (void)n_in; (void)out_size; (void)ws_size;

    const float* x    = (const float*)d_in[0];
    const float* z    = (const float*)d_in[1];
    const float* nx_b = (const float*)d_in[3];
    const float* nz_w = (const float*)d_in[4];
    const float* nz_b = (const float*)d_in[5];
    const float* t1w  = (const float*)d_in[6];
    const float* t1b  = (const float*)d_in[7];
    const float* t2w  = (const float*)d_in[8];
    const float* t2b  = (const float*)d_in[9];
    const float* p1w  = (const float*)d_in[10];
    const float* p1b  = (const float*)d_in[11];
    const float* p2w  = (const float*)d_in[12];
    const float* p2b  = (const float*)d_in[13];
    const float* g1w  = (const float*)d_in[14];
    const float* g1b  = (const float*)d_in[15];
    const float* g2w  = (const float*)d_in[16];
    const float* g2b  = (const float*)d_in[17];
    const float* ww   = (const float*)d_in[18];
    const float* wb   = (const float*)d_in[19];
    const float* vw   = (const float*)d_in[20];
    const float* vb   = (const float*)d_in[21];
    const float* pe1w = (const float*)d_in[22];
    const float* pe2w = (const float*)d_in[23];

    __half* z2   = (__half*)d_ws;
    float* stats = (float*)((char*)d_ws + Z2F * sizeof(__half));

    hipMemsetAsync(stats, 0, 1240 * sizeof(float), stream);

    dim3 grid(WW / 16, HH / 16, BN);
    dim3 blk(256);

    blockNL_k_stage1<<<grid, blk, 0, stream>>>(z, nz_w, nz_b, t1w, t1b, t2w, t2b,
                                               g1w, g1b, g2w, g2b, z2, stats);
    blockNL_k_att<<<4, 64, 0, stream>>>(nx_b, p1w, p1b, p2w, p2b, ww, wb, vw, vb,
                                        stats);
    blockNL_k_out<<<grid, blk, 0, stream>>>(x, z, vw, pe1w, pe2w, z2, stats,
                                            (float*)d_out);
}

// Round 5
// 904.766 us; speedup vs baseline: 1.0348x; 1.0348x over previous
//
#include <hip/hip_runtime.h>
#include <hip/hip_fp16.h>
#include <math.h>

// Problem constants
#define BN 4
#define CC 31
#define HH 512
#define WW 512
#define HWSZ 262144  // 512*512

// Workspace: z2 field (b,c,h,w) fp16, then float stats region.
static const size_t Z2F = (size_t)BN * CC * HWSZ;
#define T_OFF   0
#define SSQ_OFF 124
#define R0_OFF  248
#define RL_OFF  372
#define C0_OFF  496
#define CL_OFF  620
#define COR_OFF 744
#define M2_OFF  1240
#define VB2_OFF 5208

typedef short v8s __attribute__((ext_vector_type(8)));   // 8 bf16 (A/B frag)
typedef float v4f __attribute__((ext_vector_type(4)));   // 4 f32  (C/D frag)
typedef _Float16 v4h __attribute__((ext_vector_type(4))); // 4 f16 (K=16 frag)

__device__ __forceinline__ short f2bf(float f) {   // f32 -> bf16 (RNE)
    unsigned u = __float_as_uint(f);
    return (short)((u + 0x7FFFu + ((u >> 16) & 1u)) >> 16);
}

// XCD-aware swizzle: each XCD gets a contiguous 512-tile region.
__device__ __forceinline__ void swizzle_tile(int& b, int& ty0, int& tx0) {
    const int lid = blockIdx.x + 32 * blockIdx.y + 1024 * blockIdx.z;
    const int vid = ((lid & 7) << 9) + (lid >> 3);
    b = vid >> 10;
    const int rem = vid & 1023;
    ty0 = (rem >> 5) << 4;
    tx0 = (rem & 31) << 4;
}

// ---------------------------------------------------------------------------
// Kernel A: 16x16 tile, 4 blocks/CU (LDS 40576 B).
// Four 16-channel passes (T0,T1,G0,G1); per pass:
//   wbuild: 1x1 weights [16][32] bf16 -> Wp
//   mfma:   field[px][16ch] f16 (XOR half-swizzle, bank-conflict-free)
//   dw3:    16 ch per thread; T passes -> Zb + edge stats; G -> z2out global
//   stats (T only): sum/ssq MFMA on Zb, wave-pair ks split, atomic merge.
// ---------------------------------------------------------------------------
__global__ __launch_bounds__(256, 4) void blockNL_k_stage1(
    const float* __restrict__ z,
    const float* __restrict__ nz_w, const float* __restrict__ nz_b,
    const float* __restrict__ t1w, const float* __restrict__ t1b,
    const float* __restrict__ t2w, const float* __restrict__ t2b,
    const float* __restrict__ g1w, const float* __restrict__ g1b,
    const float* __restrict__ g2w, const float* __restrict__ g2b,
    __half* __restrict__ z2out, float* __restrict__ stats)
{
    __shared__ __align__(16) short Vb[324 * 32];   // LN halo, bf16 [px][32ch] 20736 B
    __shared__ __align__(16) short Wp[16 * 32];    // per-pass 1x1 W bf16      1024 B
    __shared__ __align__(16) short Ff[324 * 16];   // per-pass field f16      10368 B
    __shared__ __align__(16) short Zb[16 * 264];   // per-pass z1 bf16 stats   8448 B

    const int tid = threadIdx.x;
    int b, ty0, tx0;
    swizzle_tile(b, ty0, tx0);

    const int w = tid >> 6, lane = tid & 63, quad = lane >> 4, m15 = lane & 15;
    const int ty = tid >> 4, tx = tid & 15;
    const int gy = ty0 + ty, gx = tx0 + tx;

    // ---- phase 1: stage LN field (bf16) into Vb ----
    for (int hp = tid; hp < 324; hp += 256) {
        const int hy = hp / 18, hx = hp - hy * 18;
        const int zy = ty0 + hy - 1, zx = tx0 + hx - 1;
        const bool valid = ((unsigned)zy < (unsigned)HH) && ((unsigned)zx < (unsigned)WW);
        int pk[16];
        if (valid) {
            const float* zp = z + (size_t)b * CC * HWSZ + (size_t)zy * WW + zx;
            float v[CC];
            float mu = 0.f;
            #pragma unroll
            for (int c = 0; c < CC; ++c) { v[c] = zp[(size_t)c * HWSZ]; mu += v[c]; }
            mu *= (1.f / 31.f);
            float var = 0.f;
            #pragma unroll
            for (int c = 0; c < CC; ++c) { float d = v[c] - mu; v[c] = d; var += d * d; }
            var *= (1.f / 31.f);
            const float rs = rsqrtf(var + 1e-5f);
            #pragma unroll
            for (int c = 0; c < CC; ++c) v[c] = v[c] * rs * nz_w[c] + nz_b[c];
            #pragma unroll
            for (int i = 0; i < 16; ++i) {
                const unsigned lo = (unsigned short)f2bf(v[2 * i]);
                const unsigned hi = (2 * i + 1 < CC) ? (unsigned short)f2bf(v[2 * i + 1]) : 0u;
                pk[i] = (int)(lo | (hi << 16));
            }
        } else {
            #pragma unroll
            for (int i = 0; i < 16; ++i) pk[i] = 0;
        }
        int* dst = (int*)&Vb[hp * 32];
        #pragma unroll
        for (int q = 0; q < 4; ++q) {
            int4 t; t.x = pk[q*4]; t.y = pk[q*4+1]; t.z = pk[q*4+2]; t.w = pk[q*4+3];
            ((int4*)dst)[q] = t;
        }
    }

    // per-pass 1x1 weight tile: rows ct*16..ct*16+15 of t1w (p<2) or g1w
    auto wbuild = [&](int p) {
        const float* W1 = (p >= 2) ? g1w : t1w;
        const int ct = p & 1;
        const int m = tid >> 4, kp = tid & 15;
        const int gr = ct * 16 + m;
        const int k0 = 2 * kp, k1 = k0 + 1;
        float w0 = 0.f, w1 = 0.f;
        if (gr < CC) {
            if (k0 < CC) w0 = W1[gr * CC + k0];
            if (k1 < CC) w1 = W1[gr * CC + k1];
        }
        ((int*)Wp)[m * 16 + kp] =
            (int)((unsigned short)f2bf(w0) | ((unsigned)(unsigned short)f2bf(w1) << 16));
    };

    // MFMA matvec: field[px][16] f16; half-index XOR swizzle keyed on px bit 2
    auto mfma_pass = [&](int p) {
        const int ct = p & 1;
        const float* B1 = (p >= 2) ? g1b : t1b;
        const v8s afrag = *(const v8s*)&Wp[m15 * 32 + quad * 8];
        float bias[4];
        #pragma unroll
        for (int r = 0; r < 4; ++r) {
            const int row = ct * 16 + quad * 4 + r;
            bias[r] = (row < CC) ? B1[row] : 0.f;
        }
        for (int j = w; j < 21; j += 4) {
            const int px = j * 16 + m15;
            const int pc = (px < 324) ? px : 323;   // clamp tail (garbage, unstored)
            const v8s bfrag = *(const v8s*)&Vb[pc * 32 + quad * 8];
            v4f acc = {0.f, 0.f, 0.f, 0.f};
            acc = __builtin_amdgcn_mfma_f32_16x16x32_bf16(afrag, bfrag, acc, 0, 0, 0);
            if (px < 324) {
                unsigned d0 = (unsigned)__half_as_ushort(__float2half(acc[0] + bias[0]))
                            | ((unsigned)__half_as_ushort(__float2half(acc[1] + bias[1])) << 16);
                unsigned d1 = (unsigned)__half_as_ushort(__float2half(acc[2] + bias[2]))
                            | ((unsigned)__half_as_ushort(__float2half(acc[3] + bias[3])) << 16);
                const int half = (quad >> 1) ^ ((px >> 2) & 1);
                int2 st; st.x = (int)d0; st.y = (int)d1;
                *(int2*)&Ff[px * 16 + half * 8 + (quad & 1) * 4] = st;
            }
        }
    };

    auto dw3_pass = [&](int p) {
        const int ct = p & 1;
        const bool isG = (p >= 2);
        const float* W3 = isG ? g2w : t2w;
        const float* B3 = isG ? g2b : t2b;
        float s[16];
        #pragma unroll
        for (int r = 0; r < 16; ++r) {
            const int ch = ct * 16 + r;
            s[r] = (ch < CC) ? B3[ch] : 0.f;
        }
        #pragma unroll
        for (int dy = 0; dy < 3; ++dy)
            #pragma unroll
            for (int dx = 0; dx < 3; ++dx) {
                const int hp = (ty + dy) * 18 + (tx + dx);
                const int sel = (hp >> 2) & 1;
                const v8s f0 = *(const v8s*)&Ff[hp * 16 + sel * 8];        // ch 0-7
                const v8s f1 = *(const v8s*)&Ff[hp * 16 + (sel ^ 1) * 8];  // ch 8-15
                #pragma unroll
                for (int r = 0; r < 16; ++r) {
                    const int ch = ct * 16 + r;
                    const float wv = (ch < CC) ? W3[ch * 9 + dy * 3 + dx] : 0.f;
                    const float fv = __half2float(__ushort_as_half(
                        (unsigned short)((r < 8) ? f0[r] : f1[r - 8])));
                    s[r] += wv * fv;
                }
            }
        if (isG) {
            const size_t zbase = (size_t)b * CC * HWSZ + (size_t)gy * WW + gx;
            #pragma unroll
            for (int r = 0; r < 16; ++r) {
                const int ch = ct * 16 + r;
                if (ch < CC) z2out[zbase + (size_t)ch * HWSZ] = __float2half(s[r]);
            }
        } else {
            const bool top = (gy == 0), bot = (gy == HH - 1);
            const bool lef = (gx == 0), rig = (gx == WW - 1);
            #pragma unroll
            for (int r = 0; r < 16; ++r) {
                const int ch = ct * 16 + r;
                if (ch < CC) {
                    Zb[r * 264 + tid] = f2bf(s[r]);
                    if (top) atomicAdd(&stats[R0_OFF + b * CC + ch], s[r]);
                    if (bot) atomicAdd(&stats[RL_OFF + b * CC + ch], s[r]);
                    if (lef) atomicAdd(&stats[C0_OFF + b * CC + ch], s[r]);
                    if (rig) atomicAdd(&stats[CL_OFF + b * CC + ch], s[r]);
                    if ((top || bot) && (lef || rig))
                        stats[COR_OFF + (b * CC + ch) * 4 + (bot ? 2 : 0) + (rig ? 1 : 0)] = s[r];
                } else {
                    Zb[r * 264 + tid] = 0;   // clean pad row
                }
            }
        }
    };

    // stats: waves 0,1 = sums (ks halves), waves 2,3 = ssq (ks halves)
    auto stats_pass = [&](int ct) {
        const bool dosq = (w >> 1);
        const int kh = w & 1;
        v8s ones;
        #pragma unroll
        for (int i = 0; i < 8; ++i) ones[i] = (short)0x3F80;
        v4f acc = {0.f, 0.f, 0.f, 0.f};
        #pragma unroll
        for (int i = 0; i < 4; ++i) {
            const int ks = kh * 4 + i;
            const v8s bf = *(const v8s*)&Zb[m15 * 264 + ks * 32 + quad * 8];
            acc = __builtin_amdgcn_mfma_f32_16x16x32_bf16(dosq ? bf : ones, bf, acc, 0, 0, 0);
        }
        if (!dosq) {
            if (quad == 0) {
                const int ch = ct * 16 + m15;
                if (ch < CC) atomicAdd(&stats[T_OFF + b * CC + ch], acc[0]);
            }
        } else {
            if ((m15 >> 2) == quad) {   // diagonal lane for n = m15
                const int r = m15 & 3;
                const int ch = ct * 16 + m15;
                if (ch < CC) atomicAdd(&stats[SSQ_OFF + b * CC + ch], acc[r]);
            }
        }
    };

    wbuild(0);
    __syncthreads();
    mfma_pass(0);
    __syncthreads();
    dw3_pass(0);
    __syncthreads();
    stats_pass(0); wbuild(1);
    __syncthreads();
    mfma_pass(1);
    __syncthreads();
    dw3_pass(1);
    __syncthreads();
    stats_pass(1); wbuild(2);
    __syncthreads();
    mfma_pass(2);
    __syncthreads();
    dw3_pass(2); wbuild(3);
    __syncthreads();
    mfma_pass(3);
    __syncthreads();
    dw3_pass(3);
}

// ---------------------------------------------------------------------------
// Kernel B (4 blocks, one per batch): analytic x1, attention, fold M2/vb2.
// ---------------------------------------------------------------------------
__global__ void blockNL_k_att(
    const float* __restrict__ nx_b,
    const float* __restrict__ p1w, const float* __restrict__ p1b,
    const float* __restrict__ p2w, const float* __restrict__ p2b,
    const float* __restrict__ ww,  const float* __restrict__ wb,
    const float* __restrict__ vw,  const float* __restrict__ vb,
    float* stats)
{
    __shared__ float x1v[CC][9];
    __shared__ float dxs[CC];
    __shared__ float att[CC][CC];
    __shared__ float WA[CC][CC];

    const int tid = threadIdx.x;
    const int b = blockIdx.x;
    const float cnt[9] = {1.f, 510.f, 1.f, 510.f, 260100.f, 510.f, 1.f, 510.f, 1.f};

    if (tid < CC) {
        const float a = nx_b[0];
        const float u = p1w[tid] * a + p1b[tid];
        float w9[9];
        #pragma unroll
        for (int k = 0; k < 9; ++k) w9[k] = p2w[tid * 9 + k];
        float ssq = 0.f;
        #pragma unroll
        for (int ry = 0; ry < 3; ++ry) {
            #pragma unroll
            for (int rx = 0; rx < 3; ++rx) {
                float wsum = 0.f;
                #pragma unroll
                for (int ky = 0; ky < 3; ++ky) {
                    #pragma unroll
                    for (int kx = 0; kx < 3; ++kx) {
                        const bool okr = (ry == 1) || (ry == 0 && ky >= 1) || (ry == 2 && ky <= 1);
                        const bool okc = (rx == 1) || (rx == 0 && kx >= 1) || (rx == 2 && kx <= 1);
                        if (okr && okc) wsum += w9[ky * 3 + kx];
                    }
                }
                const float val = u * wsum + p2b[tid];
                x1v[tid][ry * 3 + rx] = val;
                ssq += cnt[ry * 3 + rx] * val * val;
            }
        }
        dxs[tid] = fmaxf(sqrtf(ssq), 1e-12f);
    }
    if (b == 0 && tid < 32) {
        float s = vb[tid];
        #pragma unroll
        for (int c = 0; c < CC; ++c) s += vw[tid * 32 + c + 1] * wb[c];
        stats[VB2_OFF + tid] = s;
    }
    __syncthreads();

    if (tid < CC) {
        const int c = tid;
        const float Tt  = stats[T_OFF  + b * CC + c];
        const float sq  = stats[SSQ_OFF + b * CC + c];
        const float r0  = stats[R0_OFF + b * CC + c];
        const float rL  = stats[RL_OFF + b * CC + c];
        const float c0  = stats[C0_OFF + b * CC + c];
        const float cL  = stats[CL_OFF + b * CC + c];
        const float k00 = stats[COR_OFF + (b * CC + c) * 4 + 0];
        const float k01 = stats[COR_OFF + (b * CC + c) * 4 + 1];
        const float k10 = stats[COR_OFF + (b * CC + c) * 4 + 2];
        const float k11 = stats[COR_OFF + (b * CC + c) * 4 + 3];
        float T[9];
        T[0] = k00; T[2] = k01; T[6] = k10; T[8] = k11;
        T[1] = r0 - k00 - k01;
        T[7] = rL - k10 - k11;
        T[3] = c0 - k00 - k10;
        T[5] = cL - k01 - k11;
        T[4] = Tt - r0 - rL - c0 - cL + k00 + k01 + k10 + k11;
        const float dz = fmaxf(sqrtf(sq), 1e-12f);

        float Arow[CC];
        float mx = -3.4e38f;
        #pragma unroll
        for (int d = 0; d < CC; ++d) {
            float s = 0.f;
            #pragma unroll
            for (int r = 0; r < 9; ++r) s += T[r] * x1v[d][r];
            s = s / (dz * dxs[d]);
            Arow[d] = s;
            mx = fmaxf(mx, s);
        }
        float den = 0.f;
        #pragma unroll
        for (int d = 0; d < CC; ++d) { float e = expf(Arow[d] - mx); Arow[d] = e; den += e; }
        const float inv = 1.f / den;
        #pragma unroll
        for (int d = 0; d < CC; ++d) att[c][d] = Arow[d] * inv;
    }
    __syncthreads();
    if (tid < CC) {
        const int c2 = tid;
        #pragma unroll
        for (int d = 0; d < CC; ++d) {
            float s = 0.f;
            #pragma unroll
            for (int c = 0; c < CC; ++c) s += ww[c2 * CC + c] * att[c][d];
            WA[c2][d] = s;
        }
    }
    __syncthreads();
    if (tid < 32) {
        const int e = tid;
        #pragma unroll
        for (int d = 0; d < CC; ++d) {
            float s = 0.f;
            #pragma unroll
            for (int c2 = 0; c2 < CC; ++c2) s += vw[e * 32 + c2 + 1] * WA[c2][d];
            stats[M2_OFF + (b * 32 + e) * CC + d] = s;
        }
    }
}

// ---------------------------------------------------------------------------
// Kernel C: 16x16 tile. Per 8-ch chunk: z2 (halo2, RAW fp16 LDS), q=gelu(dw3)
// (fp16 LDS), pos=dw3(q); per-chunk U[256 px][16] fp16 = [pos+z(8) ; z2(8)],
// accumulate epilogue GEMM with K=16 fp16 MFMA per chunk (acc in VGPRs).
// LDS: 6400(zbh) + 5184(qbh) + 10240(Ub) + 1024(A2c) = 22848 B.
// launch_bounds(256,6): VGPR cap ~85 (round-3 alloc was 64 -> no spills);
// (256,7)'s cap of 73 spilled the acc[8] accumulator to scratch (+1 GB HBM).
// ---------------------------------------------------------------------------
__global__ __launch_bounds__(256, 6) void blockNL_k_out(
    const float* __restrict__ x, const float* __restrict__ z,
    const float* __restrict__ vw,
    const float* __restrict__ pe1w, const float* __restrict__ pe2w,
    const __half* __restrict__ z2, const float* __restrict__ stats,
    float* __restrict__ out)
{
    __shared__ __align__(16) short zbh[8][400];     // 20x20 z2 chunk, raw fp16
    __shared__ __align__(16) short qbh[8][324];     // 18x18 gelu chunk, fp16
    __shared__ __align__(16) short Ub[256 * 20];    // per-chunk U [px][16+pad] f16
    __shared__ __align__(16) short A2c[32 * 16];    // per-chunk A [e][16] f16

    const int tid = threadIdx.x;
    int b, ty0, tx0;
    swizzle_tile(b, ty0, tx0);
    const int ty = tid >> 4, tx = tid & 15;
    const int gy = ty0 + ty, gx = tx0 + tx;

    const float* M2 = stats + M2_OFF + b * 32 * CC;

    const int w = tid >> 6, lane = tid & 63, quad = lane >> 4, m15 = lane & 15;
    const int mt = w & 1, jbase = (w >> 1) * 8;
    const size_t zpix = (size_t)b * CC * HWSZ + (size_t)gy * WW + gx;

    v4f acc[8];
    #pragma unroll
    for (int jj = 0; jj < 8; ++jj) acc[jj] = (v4f){0.f, 0.f, 0.f, 0.f};

    // stage z2 chunk ci into zbh (raw fp16; zero outside / pad channel)
    auto stage = [&](int ci) {
        for (int idx = tid; idx < 3200; idx += 256) {
            const int c8 = idx / 400, p = idx - c8 * 400;
            const int ch = ci * 8 + c8;
            const int hy = p / 20, hx = p - hy * 20;
            const int zy = ty0 + hy - 2, zx = tx0 + hx - 2;
            unsigned short v = 0;
            if (ch < 31 && (unsigned)zy < (unsigned)HH && (unsigned)zx < (unsigned)WW)
                v = __half_as_ushort(z2[((size_t)(b * CC + ch)) * HWSZ + (size_t)zy * WW + zx]);
            zbh[c8][p] = (short)v;
        }
    };

    stage(0);

    for (int ci = 0; ci < 4; ++ci) {
        __syncthreads();   // zbh(ci) staged
        // q = gelu(dw3(z2, pe1)) on 18x18 halo-1 -> qbh fp16
        for (int idx = tid; idx < 2592; idx += 256) {
            const int c8 = idx / 324, p = idx - c8 * 324;
            const int ch = ci * 8 + c8;
            const int hy = p / 18, hx = p - hy * 18;
            const int qy = ty0 + hy - 1, qx = tx0 + hx - 1;
            float q = 0.f;
            if ((unsigned)qy < (unsigned)HH && (unsigned)qx < (unsigned)WW) {
                float s = 0.f;
                #pragma unroll
                for (int dy = 0; dy < 3; ++dy)
                    #pragma unroll
                    for (int dx = 0; dx < 3; ++dx) {
                        const float wv = (ch < 31) ? pe1w[ch * 9 + dy * 3 + dx] : 0.f;
                        s += wv * __half2float(__ushort_as_half(
                                 (unsigned short)zbh[c8][(hy + dy) * 20 + hx + dx]));
                    }
                q = 0.5f * s * (1.f + erff(s * 0.70710678118654752f));
            }
            qbh[c8][p] = (short)__half_as_ushort(__float2half(q));
        }
        __syncthreads();
        // A2c chunk build: k<8 -> vv[e][ci*8+k]; k>=8 -> M2[e][ci*8+k-8]
        // (prev MFMA's A2c reads finished 2 barriers ago; next read after barrier)
        for (int idx = tid; idx < 512; idx += 256) {
            const int e = idx >> 4, k = idx & 15;
            const int ch = ci * 8 + (k & 7);
            float v = 0.f;
            if (ch < 31) v = (k < 8) ? vw[e * 32 + 1 + ch] : M2[e * CC + ch];
            A2c[e * 16 + k] = (short)__half_as_ushort(__float2half(v));
        }
        // pos = dw3(q, pe2); per-chunk U row (fp16): [pos+z | z2-center(raw)]
        {
            unsigned pk[8];
            #pragma unroll
            for (int r = 0; r < 8; ++r) {
                const int ch = ci * 8 + r;
                float tval = 0.f;
                unsigned zvh = 0;
                if (ch < 31) {
                    float pos = 0.f;
                    #pragma unroll
                    for (int dy = 0; dy < 3; ++dy)
                        #pragma unroll
                        for (int dx = 0; dx < 3; ++dx)
                            pos += pe2w[ch * 9 + dy * 3 + dx] *
                                   __half2float(__ushort_as_half(
                                       (unsigned short)qbh[r][(ty + dy) * 18 + (tx + dx)]));
                    tval = pos + z[zpix + (size_t)ch * HWSZ];
                    zvh = (unsigned)(unsigned short)zbh[r][(ty + 2) * 20 + (tx + 2)];
                }
                pk[r] = (unsigned)__half_as_ushort(__float2half(tval)) | (zvh << 16);
            }
            // interleave: cols 0-7 = tval (pk low), cols 8-15 = zval (pk high)
            int* ub = (int*)&Ub[tid * 20];
            int2 s0, s1, s2, s3;
            s0.x = (int)((pk[0] & 0xFFFFu) | (pk[1] << 16));
            s0.y = (int)((pk[2] & 0xFFFFu) | (pk[3] << 16));
            s1.x = (int)((pk[4] & 0xFFFFu) | (pk[5] << 16));
            s1.y = (int)((pk[6] & 0xFFFFu) | (pk[7] << 16));
            s2.x = (int)((pk[0] >> 16) | (pk[1] & 0xFFFF0000u));
            s2.y = (int)((pk[2] >> 16) | (pk[3] & 0xFFFF0000u));
            s3.x = (int)((pk[4] >> 16) | (pk[5] & 0xFFFF0000u));
            s3.y = (int)((pk[6] >> 16) | (pk[7] & 0xFFFF0000u));
            ((int2*)ub)[0] = s0;
            ((int2*)ub)[1] = s1;
            ((int2*)ub)[2] = s2;
            ((int2*)ub)[3] = s3;
        }
        __syncthreads();   // Ub + A2c ready; zbh consumed -> restage under MFMA
        // partial epilogue GEMM: acc += A2c @ U(ci)   (K=16 fp16 MFMA)
        {
            const v4h a = *(const v4h*)&A2c[(mt * 16 + m15) * 16 + quad * 4];
            #pragma unroll
            for (int jj = 0; jj < 8; ++jj) {
                const int p = (jbase + jj) * 16 + m15;
                const v4h bv = *(const v4h*)&Ub[p * 20 + quad * 4];
                acc[jj] = __builtin_amdgcn_mfma_f32_16x16x16f16(a, bv, acc[jj], 0, 0, 0);
            }
        }
        if (ci < 3) stage(ci + 1);
    }

    // ---- epilogue: out = acc + vb2 + vw0*x ----
    {
        float vb2r[4], vw0[4];
        #pragma unroll
        for (int r = 0; r < 4; ++r) {
            const int e = mt * 16 + quad * 4 + r;
            vb2r[r] = stats[VB2_OFF + e];
            vw0[r]  = vw[e * 32];
        }
        #pragma unroll
        for (int jj = 0; jj < 8; ++jj) {
            const int p = (jbase + jj) * 16 + m15;
            const int py = p >> 4, px = p & 15;
            const int ogy = ty0 + py, ogx = tx0 + px;
            const float xv = x[(size_t)b * HWSZ + (size_t)ogy * WW + ogx];
            const size_t obase = (size_t)b * 32 * HWSZ + (size_t)ogy * WW + ogx;
            #pragma unroll
            for (int r = 0; r < 4; ++r) {
                const int e = mt * 16 + quad * 4 + r;
                out[obase + (size_t)e * HWSZ] = acc[jj][r] + vb2r[r] + vw0[r] * xv;
            }
        }
    }
}

// ---------------------------------------------------------------------------
extern "C" void kernel_launch(void* const* d_in, const int* in_sizes, int n_in,
                              void* d_out, int out_size, void* d_ws, size_t ws_size,
                              hipStream_t stream)
{
    (void)in_sizes; (void)n_in; (void)out_size; (void)ws_size;

    const float* x    = (const float*)d_in[0];
    const float* z    = (const float*)d_in[1];
    const float* nx_b = (const float*)d_in[3];
    const float* nz_w = (const float*)d_in[4];
    const float* nz_b = (const float*)d_in[5];
    const float* t1w  = (const float*)d_in[6];
    const float* t1b  = (const float*)d_in[7];
    const float* t2w  = (const float*)d_in[8];
    const float* t2b  = (const float*)d_in[9];
    const float* p1w  = (const float*)d_in[10];
    const float* p1b  = (const float*)d_in[11];
    const float* p2w  = (const float*)d_in[12];
    const float* p2b  = (const float*)d_in[13];
    const float* g1w  = (const float*)d_in[14];
    const float* g1b  = (const float*)d_in[15];
    const float* g2w  = (const float*)d_in[16];
    const float* g2b  = (const float*)d_in[17];
    const float* ww   = (const float*)d_in[18];
    const float* wb   = (const float*)d_in[19];
    const float* vw   = (const float*)d_in[20];
    const float* vb   = (const float*)d_in[21];
    const float* pe1w = (const float*)d_in[22];
    const float* pe2w = (const float*)d_in[23];

    __half* z2   = (__half*)d_ws;
    float* stats = (float*)((char*)d_ws + Z2F * sizeof(__half));

    hipMemsetAsync(stats, 0, 1240 * sizeof(float), stream);

    dim3 grid(WW / 16, HH / 16, BN);
    dim3 blk(256);

    blockNL_k_stage1<<<grid, blk, 0, stream>>>(z, nz_w, nz_b, t1w, t1b, t2w, t2b,
                                               g1w, g1b, g2w, g2b, z2, stats);
    blockNL_k_att<<<4, 64, 0, stream>>>(nx_b, p1w, p1b, p2w, p2b, ww, wb, vw, vb,
                                        stats);
    blockNL_k_out<<<grid, blk, 0, stream>>>(x, z, vw, pe1w, pe2w, z2, stats,
                                            (float*)d_out);
}

// Round 6
// 796.750 us; speedup vs baseline: 1.1751x; 1.1356x over previous
//
#include <hip/hip_runtime.h>
#include <hip/hip_fp16.h>
#include <math.h>

// Problem constants
#define BN 4
#define CC 31
#define HH 512
#define WW 512
#define HWSZ 262144  // 512*512

// Workspace: z2 field (b,c,h,w) fp16, then float stats region.
static const size_t Z2F = (size_t)BN * CC * HWSZ;
#define T_OFF   0
#define SSQ_OFF 124
#define R0_OFF  248
#define RL_OFF  372
#define C0_OFF  496
#define CL_OFF  620
#define COR_OFF 744
#define M2_OFF  1240
#define VB2_OFF 5208

typedef short v8s __attribute__((ext_vector_type(8)));   // 8 bf16 (A/B frag)
typedef float v4f __attribute__((ext_vector_type(4)));   // 4 f32  (C/D frag)
typedef _Float16 v4h __attribute__((ext_vector_type(4))); // 4 f16 (K=16 frag)

__device__ __forceinline__ short f2bf(float f) {   // f32 -> bf16 (RNE)
    unsigned u = __float_as_uint(f);
    return (short)((u + 0x7FFFu + ((u >> 16) & 1u)) >> 16);
}

// XCD-aware swizzle: each XCD gets a contiguous 512-tile region.
__device__ __forceinline__ void swizzle_tile(int& b, int& ty0, int& tx0) {
    const int lid = blockIdx.x + 32 * blockIdx.y + 1024 * blockIdx.z;
    const int vid = ((lid & 7) << 9) + (lid >> 3);
    b = vid >> 10;
    const int rem = vid & 1023;
    ty0 = (rem >> 5) << 4;
    tx0 = (rem & 31) << 4;
}

// ---------------------------------------------------------------------------
// Kernel A: 16x16 tile, 4 blocks/CU (LDS 40576 B).
// Four 16-channel passes (T0,T1,G0,G1); per pass:
//   wbuild: 1x1 weights [16][32] bf16 -> Wp
//   mfma:   field[px][16ch] f16 (XOR half-swizzle, bank-conflict-free)
//   dw3:    16 ch per thread; T passes -> Zb + edge stats; G -> z2out global
//   stats (T only): sum/ssq MFMA on Zb, wave-pair ks split, atomic merge.
// ---------------------------------------------------------------------------
__global__ __launch_bounds__(256, 4) void blockNL_k_stage1(
    const float* __restrict__ z,
    const float* __restrict__ nz_w, const float* __restrict__ nz_b,
    const float* __restrict__ t1w, const float* __restrict__ t1b,
    const float* __restrict__ t2w, const float* __restrict__ t2b,
    const float* __restrict__ g1w, const float* __restrict__ g1b,
    const float* __restrict__ g2w, const float* __restrict__ g2b,
    __half* __restrict__ z2out, float* __restrict__ stats)
{
    __shared__ __align__(16) short Vb[324 * 32];   // LN halo, bf16 [px][32ch] 20736 B
    __shared__ __align__(16) short Wp[16 * 32];    // per-pass 1x1 W bf16      1024 B
    __shared__ __align__(16) short Ff[324 * 16];   // per-pass field f16      10368 B
    __shared__ __align__(16) short Zb[16 * 264];   // per-pass z1 bf16 stats   8448 B

    const int tid = threadIdx.x;
    int b, ty0, tx0;
    swizzle_tile(b, ty0, tx0);

    const int w = tid >> 6, lane = tid & 63, quad = lane >> 4, m15 = lane & 15;
    const int ty = tid >> 4, tx = tid & 15;
    const int gy = ty0 + ty, gx = tx0 + tx;

    // ---- phase 1: stage LN field (bf16) into Vb ----
    for (int hp = tid; hp < 324; hp += 256) {
        const int hy = hp / 18, hx = hp - hy * 18;
        const int zy = ty0 + hy - 1, zx = tx0 + hx - 1;
        const bool valid = ((unsigned)zy < (unsigned)HH) && ((unsigned)zx < (unsigned)WW);
        int pk[16];
        if (valid) {
            const float* zp = z + (size_t)b * CC * HWSZ + (size_t)zy * WW + zx;
            float v[CC];
            float mu = 0.f;
            #pragma unroll
            for (int c = 0; c < CC; ++c) { v[c] = zp[(size_t)c * HWSZ]; mu += v[c]; }
            mu *= (1.f / 31.f);
            float var = 0.f;
            #pragma unroll
            for (int c = 0; c < CC; ++c) { float d = v[c] - mu; v[c] = d; var += d * d; }
            var *= (1.f / 31.f);
            const float rs = rsqrtf(var + 1e-5f);
            #pragma unroll
            for (int c = 0; c < CC; ++c) v[c] = v[c] * rs * nz_w[c] + nz_b[c];
            #pragma unroll
            for (int i = 0; i < 16; ++i) {
                const unsigned lo = (unsigned short)f2bf(v[2 * i]);
                const unsigned hi = (2 * i + 1 < CC) ? (unsigned short)f2bf(v[2 * i + 1]) : 0u;
                pk[i] = (int)(lo | (hi << 16));
            }
        } else {
            #pragma unroll
            for (int i = 0; i < 16; ++i) pk[i] = 0;
        }
        int* dst = (int*)&Vb[hp * 32];
        #pragma unroll
        for (int q = 0; q < 4; ++q) {
            int4 t; t.x = pk[q*4]; t.y = pk[q*4+1]; t.z = pk[q*4+2]; t.w = pk[q*4+3];
            ((int4*)dst)[q] = t;
        }
    }

    // per-pass 1x1 weight tile: rows ct*16..ct*16+15 of t1w (p<2) or g1w
    auto wbuild = [&](int p) {
        const float* W1 = (p >= 2) ? g1w : t1w;
        const int ct = p & 1;
        const int m = tid >> 4, kp = tid & 15;
        const int gr = ct * 16 + m;
        const int k0 = 2 * kp, k1 = k0 + 1;
        float w0 = 0.f, w1 = 0.f;
        if (gr < CC) {
            if (k0 < CC) w0 = W1[gr * CC + k0];
            if (k1 < CC) w1 = W1[gr * CC + k1];
        }
        ((int*)Wp)[m * 16 + kp] =
            (int)((unsigned short)f2bf(w0) | ((unsigned)(unsigned short)f2bf(w1) << 16));
    };

    // MFMA matvec: field[px][16] f16; half-index XOR swizzle keyed on px bit 2
    auto mfma_pass = [&](int p) {
        const int ct = p & 1;
        const float* B1 = (p >= 2) ? g1b : t1b;
        const v8s afrag = *(const v8s*)&Wp[m15 * 32 + quad * 8];
        float bias[4];
        #pragma unroll
        for (int r = 0; r < 4; ++r) {
            const int row = ct * 16 + quad * 4 + r;
            bias[r] = (row < CC) ? B1[row] : 0.f;
        }
        for (int j = w; j < 21; j += 4) {
            const int px = j * 16 + m15;
            const int pc = (px < 324) ? px : 323;   // clamp tail (garbage, unstored)
            const v8s bfrag = *(const v8s*)&Vb[pc * 32 + quad * 8];
            v4f acc = {0.f, 0.f, 0.f, 0.f};
            acc = __builtin_amdgcn_mfma_f32_16x16x32_bf16(afrag, bfrag, acc, 0, 0, 0);
            if (px < 324) {
                unsigned d0 = (unsigned)__half_as_ushort(__float2half(acc[0] + bias[0]))
                            | ((unsigned)__half_as_ushort(__float2half(acc[1] + bias[1])) << 16);
                unsigned d1 = (unsigned)__half_as_ushort(__float2half(acc[2] + bias[2]))
                            | ((unsigned)__half_as_ushort(__float2half(acc[3] + bias[3])) << 16);
                const int half = (quad >> 1) ^ ((px >> 2) & 1);
                int2 st; st.x = (int)d0; st.y = (int)d1;
                *(int2*)&Ff[px * 16 + half * 8 + (quad & 1) * 4] = st;
            }
        }
    };

    auto dw3_pass = [&](int p) {
        const int ct = p & 1;
        const bool isG = (p >= 2);
        const float* W3 = isG ? g2w : t2w;
        const float* B3 = isG ? g2b : t2b;
        float s[16];
        #pragma unroll
        for (int r = 0; r < 16; ++r) {
            const int ch = ct * 16 + r;
            s[r] = (ch < CC) ? B3[ch] : 0.f;
        }
        #pragma unroll
        for (int dy = 0; dy < 3; ++dy)
            #pragma unroll
            for (int dx = 0; dx < 3; ++dx) {
                const int hp = (ty + dy) * 18 + (tx + dx);
                const int sel = (hp >> 2) & 1;
                const v8s f0 = *(const v8s*)&Ff[hp * 16 + sel * 8];        // ch 0-7
                const v8s f1 = *(const v8s*)&Ff[hp * 16 + (sel ^ 1) * 8];  // ch 8-15
                #pragma unroll
                for (int r = 0; r < 16; ++r) {
                    const int ch = ct * 16 + r;
                    const float wv = (ch < CC) ? W3[ch * 9 + dy * 3 + dx] : 0.f;
                    const float fv = __half2float(__ushort_as_half(
                        (unsigned short)((r < 8) ? f0[r] : f1[r - 8])));
                    s[r] += wv * fv;
                }
            }
        if (isG) {
            const size_t zbase = (size_t)b * CC * HWSZ + (size_t)gy * WW + gx;
            #pragma unroll
            for (int r = 0; r < 16; ++r) {
                const int ch = ct * 16 + r;
                if (ch < CC) z2out[zbase + (size_t)ch * HWSZ] = __float2half(s[r]);
            }
        } else {
            const bool top = (gy == 0), bot = (gy == HH - 1);
            const bool lef = (gx == 0), rig = (gx == WW - 1);
            #pragma unroll
            for (int r = 0; r < 16; ++r) {
                const int ch = ct * 16 + r;
                if (ch < CC) {
                    Zb[r * 264 + tid] = f2bf(s[r]);
                    if (top) atomicAdd(&stats[R0_OFF + b * CC + ch], s[r]);
                    if (bot) atomicAdd(&stats[RL_OFF + b * CC + ch], s[r]);
                    if (lef) atomicAdd(&stats[C0_OFF + b * CC + ch], s[r]);
                    if (rig) atomicAdd(&stats[CL_OFF + b * CC + ch], s[r]);
                    if ((top || bot) && (lef || rig))
                        stats[COR_OFF + (b * CC + ch) * 4 + (bot ? 2 : 0) + (rig ? 1 : 0)] = s[r];
                } else {
                    Zb[r * 264 + tid] = 0;   // clean pad row
                }
            }
        }
    };

    // stats: waves 0,1 = sums (ks halves), waves 2,3 = ssq (ks halves)
    auto stats_pass = [&](int ct) {
        const bool dosq = (w >> 1);
        const int kh = w & 1;
        v8s ones;
        #pragma unroll
        for (int i = 0; i < 8; ++i) ones[i] = (short)0x3F80;
        v4f acc = {0.f, 0.f, 0.f, 0.f};
        #pragma unroll
        for (int i = 0; i < 4; ++i) {
            const int ks = kh * 4 + i;
            const v8s bf = *(const v8s*)&Zb[m15 * 264 + ks * 32 + quad * 8];
            acc = __builtin_amdgcn_mfma_f32_16x16x32_bf16(dosq ? bf : ones, bf, acc, 0, 0, 0);
        }
        if (!dosq) {
            if (quad == 0) {
                const int ch = ct * 16 + m15;
                if (ch < CC) atomicAdd(&stats[T_OFF + b * CC + ch], acc[0]);
            }
        } else {
            if ((m15 >> 2) == quad) {   // diagonal lane for n = m15
                const int r = m15 & 3;
                const int ch = ct * 16 + m15;
                if (ch < CC) atomicAdd(&stats[SSQ_OFF + b * CC + ch], acc[r]);
            }
        }
    };

    wbuild(0);
    __syncthreads();
    mfma_pass(0);
    __syncthreads();
    dw3_pass(0);
    __syncthreads();
    stats_pass(0); wbuild(1);
    __syncthreads();
    mfma_pass(1);
    __syncthreads();
    dw3_pass(1);
    __syncthreads();
    stats_pass(1); wbuild(2);
    __syncthreads();
    mfma_pass(2);
    __syncthreads();
    dw3_pass(2); wbuild(3);
    __syncthreads();
    mfma_pass(3);
    __syncthreads();
    dw3_pass(3);
}

// ---------------------------------------------------------------------------
// Kernel B (4 blocks, one per batch): analytic x1, attention, fold M2/vb2.
// ---------------------------------------------------------------------------
__global__ void blockNL_k_att(
    const float* __restrict__ nx_b,
    const float* __restrict__ p1w, const float* __restrict__ p1b,
    const float* __restrict__ p2w, const float* __restrict__ p2b,
    const float* __restrict__ ww,  const float* __restrict__ wb,
    const float* __restrict__ vw,  const float* __restrict__ vb,
    float* stats)
{
    __shared__ float x1v[CC][9];
    __shared__ float dxs[CC];
    __shared__ float att[CC][CC];
    __shared__ float WA[CC][CC];

    const int tid = threadIdx.x;
    const int b = blockIdx.x;
    const float cnt[9] = {1.f, 510.f, 1.f, 510.f, 260100.f, 510.f, 1.f, 510.f, 1.f};

    if (tid < CC) {
        const float a = nx_b[0];
        const float u = p1w[tid] * a + p1b[tid];
        float w9[9];
        #pragma unroll
        for (int k = 0; k < 9; ++k) w9[k] = p2w[tid * 9 + k];
        float ssq = 0.f;
        #pragma unroll
        for (int ry = 0; ry < 3; ++ry) {
            #pragma unroll
            for (int rx = 0; rx < 3; ++rx) {
                float wsum = 0.f;
                #pragma unroll
                for (int ky = 0; ky < 3; ++ky) {
                    #pragma unroll
                    for (int kx = 0; kx < 3; ++kx) {
                        const bool okr = (ry == 1) || (ry == 0 && ky >= 1) || (ry == 2 && ky <= 1);
                        const bool okc = (rx == 1) || (rx == 0 && kx >= 1) || (rx == 2 && kx <= 1);
                        if (okr && okc) wsum += w9[ky * 3 + kx];
                    }
                }
                const float val = u * wsum + p2b[tid];
                x1v[tid][ry * 3 + rx] = val;
                ssq += cnt[ry * 3 + rx] * val * val;
            }
        }
        dxs[tid] = fmaxf(sqrtf(ssq), 1e-12f);
    }
    if (b == 0 && tid < 32) {
        float s = vb[tid];
        #pragma unroll
        for (int c = 0; c < CC; ++c) s += vw[tid * 32 + c + 1] * wb[c];
        stats[VB2_OFF + tid] = s;
    }
    __syncthreads();

    if (tid < CC) {
        const int c = tid;
        const float Tt  = stats[T_OFF  + b * CC + c];
        const float sq  = stats[SSQ_OFF + b * CC + c];
        const float r0  = stats[R0_OFF + b * CC + c];
        const float rL  = stats[RL_OFF + b * CC + c];
        const float c0  = stats[C0_OFF + b * CC + c];
        const float cL  = stats[CL_OFF + b * CC + c];
        const float k00 = stats[COR_OFF + (b * CC + c) * 4 + 0];
        const float k01 = stats[COR_OFF + (b * CC + c) * 4 + 1];
        const float k10 = stats[COR_OFF + (b * CC + c) * 4 + 2];
        const float k11 = stats[COR_OFF + (b * CC + c) * 4 + 3];
        float T[9];
        T[0] = k00; T[2] = k01; T[6] = k10; T[8] = k11;
        T[1] = r0 - k00 - k01;
        T[7] = rL - k10 - k11;
        T[3] = c0 - k00 - k10;
        T[5] = cL - k01 - k11;
        T[4] = Tt - r0 - rL - c0 - cL + k00 + k01 + k10 + k11;
        const float dz = fmaxf(sqrtf(sq), 1e-12f);

        float Arow[CC];
        float mx = -3.4e38f;
        #pragma unroll
        for (int d = 0; d < CC; ++d) {
            float s = 0.f;
            #pragma unroll
            for (int r = 0; r < 9; ++r) s += T[r] * x1v[d][r];
            s = s / (dz * dxs[d]);
            Arow[d] = s;
            mx = fmaxf(mx, s);
        }
        float den = 0.f;
        #pragma unroll
        for (int d = 0; d < CC; ++d) { float e = expf(Arow[d] - mx); Arow[d] = e; den += e; }
        const float inv = 1.f / den;
        #pragma unroll
        for (int d = 0; d < CC; ++d) att[c][d] = Arow[d] * inv;
    }
    __syncthreads();
    if (tid < CC) {
        const int c2 = tid;
        #pragma unroll
        for (int d = 0; d < CC; ++d) {
            float s = 0.f;
            #pragma unroll
            for (int c = 0; c < CC; ++c) s += ww[c2 * CC + c] * att[c][d];
            WA[c2][d] = s;
        }
    }
    __syncthreads();
    if (tid < 32) {
        const int e = tid;
        #pragma unroll
        for (int d = 0; d < CC; ++d) {
            float s = 0.f;
            #pragma unroll
            for (int c2 = 0; c2 < CC; ++c2) s += vw[e * 32 + c2 + 1] * WA[c2][d];
            stats[M2_OFF + (b * 32 + e) * CC + d] = s;
        }
    }
}

// ---------------------------------------------------------------------------
// Kernel C: 16x16 tile. Per 8-ch chunk: z2 (halo2, RAW fp16 LDS), q=gelu(dw3)
// (fp16 LDS), pos=dw3(q); per-chunk U[256 px][16] fp16 = [pos+z(8) ; z2(8)],
// accumulate epilogue GEMM with K=16 fp16 MFMA per chunk (acc in VGPRs).
// LDS: 6400(zbh) + 5184(qbh) + 10240(Ub) + 1024(A2c) = 22848 B.
// launch_bounds(256,4): min-waves promise only -- hardware occupancy derives
// from actual usage: ~64 VGPR -> 7 blocks/CU via LDS limit. Demanding 6-7
// waves/EU made LLVM spill the acc[8] accumulator to scratch (rounds 4-5:
// VGPR_Count 36/40, +900 MB HBM spill traffic). Cap must stay >= real need.
// ---------------------------------------------------------------------------
__global__ __launch_bounds__(256, 4) void blockNL_k_out(
    const float* __restrict__ x, const float* __restrict__ z,
    const float* __restrict__ vw,
    const float* __restrict__ pe1w, const float* __restrict__ pe2w,
    const __half* __restrict__ z2, const float* __restrict__ stats,
    float* __restrict__ out)
{
    __shared__ __align__(16) short zbh[8][400];     // 20x20 z2 chunk, raw fp16
    __shared__ __align__(16) short qbh[8][324];     // 18x18 gelu chunk, fp16
    __shared__ __align__(16) short Ub[256 * 20];    // per-chunk U [px][16+pad] f16
    __shared__ __align__(16) short A2c[32 * 16];    // per-chunk A [e][16] f16

    const int tid = threadIdx.x;
    int b, ty0, tx0;
    swizzle_tile(b, ty0, tx0);
    const int ty = tid >> 4, tx = tid & 15;
    const int gy = ty0 + ty, gx = tx0 + tx;

    const float* M2 = stats + M2_OFF + b * 32 * CC;

    const int w = tid >> 6, lane = tid & 63, quad = lane >> 4, m15 = lane & 15;
    const int mt = w & 1, jbase = (w >> 1) * 8;
    const size_t zpix = (size_t)b * CC * HWSZ + (size_t)gy * WW + gx;

    v4f acc[8];
    #pragma unroll
    for (int jj = 0; jj < 8; ++jj) acc[jj] = (v4f){0.f, 0.f, 0.f, 0.f};

    // stage z2 chunk ci into zbh (raw fp16; zero outside / pad channel)
    auto stage = [&](int ci) {
        for (int idx = tid; idx < 3200; idx += 256) {
            const int c8 = idx / 400, p = idx - c8 * 400;
            const int ch = ci * 8 + c8;
            const int hy = p / 20, hx = p - hy * 20;
            const int zy = ty0 + hy - 2, zx = tx0 + hx - 2;
            unsigned short v = 0;
            if (ch < 31 && (unsigned)zy < (unsigned)HH && (unsigned)zx < (unsigned)WW)
                v = __half_as_ushort(z2[((size_t)(b * CC + ch)) * HWSZ + (size_t)zy * WW + zx]);
            zbh[c8][p] = (short)v;
        }
    };

    stage(0);

    for (int ci = 0; ci < 4; ++ci) {
        __syncthreads();   // zbh(ci) staged
        // q = gelu(dw3(z2, pe1)) on 18x18 halo-1 -> qbh fp16
        for (int idx = tid; idx < 2592; idx += 256) {
            const int c8 = idx / 324, p = idx - c8 * 324;
            const int ch = ci * 8 + c8;
            const int hy = p / 18, hx = p - hy * 18;
            const int qy = ty0 + hy - 1, qx = tx0 + hx - 1;
            float q = 0.f;
            if ((unsigned)qy < (unsigned)HH && (unsigned)qx < (unsigned)WW) {
                float s = 0.f;
                #pragma unroll
                for (int dy = 0; dy < 3; ++dy)
                    #pragma unroll
                    for (int dx = 0; dx < 3; ++dx) {
                        const float wv = (ch < 31) ? pe1w[ch * 9 + dy * 3 + dx] : 0.f;
                        s += wv * __half2float(__ushort_as_half(
                                 (unsigned short)zbh[c8][(hy + dy) * 20 + hx + dx]));
                    }
                q = 0.5f * s * (1.f + erff(s * 0.70710678118654752f));
            }
            qbh[c8][p] = (short)__half_as_ushort(__float2half(q));
        }
        __syncthreads();
        // A2c chunk build: k<8 -> vv[e][ci*8+k]; k>=8 -> M2[e][ci*8+k-8]
        // (prev MFMA's A2c reads finished 2 barriers ago; next read after barrier)
        for (int idx = tid; idx < 512; idx += 256) {
            const int e = idx >> 4, k = idx & 15;
            const int ch = ci * 8 + (k & 7);
            float v = 0.f;
            if (ch < 31) v = (k < 8) ? vw[e * 32 + 1 + ch] : M2[e * CC + ch];
            A2c[e * 16 + k] = (short)__half_as_ushort(__float2half(v));
        }
        // pos = dw3(q, pe2); per-chunk U row (fp16): [pos+z | z2-center(raw)]
        {
            unsigned pk[8];
            #pragma unroll
            for (int r = 0; r < 8; ++r) {
                const int ch = ci * 8 + r;
                float tval = 0.f;
                unsigned zvh = 0;
                if (ch < 31) {
                    float pos = 0.f;
                    #pragma unroll
                    for (int dy = 0; dy < 3; ++dy)
                        #pragma unroll
                        for (int dx = 0; dx < 3; ++dx)
                            pos += pe2w[ch * 9 + dy * 3 + dx] *
                                   __half2float(__ushort_as_half(
                                       (unsigned short)qbh[r][(ty + dy) * 18 + (tx + dx)]));
                    tval = pos + z[zpix + (size_t)ch * HWSZ];
                    zvh = (unsigned)(unsigned short)zbh[r][(ty + 2) * 20 + (tx + 2)];
                }
                pk[r] = (unsigned)__half_as_ushort(__float2half(tval)) | (zvh << 16);
            }
            // interleave: cols 0-7 = tval (pk low), cols 8-15 = zval (pk high)
            int* ub = (int*)&Ub[tid * 20];
            int2 s0, s1, s2, s3;
            s0.x = (int)((pk[0] & 0xFFFFu) | (pk[1] << 16));
            s0.y = (int)((pk[2] & 0xFFFFu) | (pk[3] << 16));
            s1.x = (int)((pk[4] & 0xFFFFu) | (pk[5] << 16));
            s1.y = (int)((pk[6] & 0xFFFFu) | (pk[7] << 16));
            s2.x = (int)((pk[0] >> 16) | (pk[1] & 0xFFFF0000u));
            s2.y = (int)((pk[2] >> 16) | (pk[3] & 0xFFFF0000u));
            s3.x = (int)((pk[4] >> 16) | (pk[5] & 0xFFFF0000u));
            s3.y = (int)((pk[6] >> 16) | (pk[7] & 0xFFFF0000u));
            ((int2*)ub)[0] = s0;
            ((int2*)ub)[1] = s1;
            ((int2*)ub)[2] = s2;
            ((int2*)ub)[3] = s3;
        }
        __syncthreads();   // Ub + A2c ready; zbh consumed -> restage under MFMA
        // partial epilogue GEMM: acc += A2c @ U(ci)   (K=16 fp16 MFMA)
        {
            const v4h a = *(const v4h*)&A2c[(mt * 16 + m15) * 16 + quad * 4];
            #pragma unroll
            for (int jj = 0; jj < 8; ++jj) {
                const int p = (jbase + jj) * 16 + m15;
                const v4h bv = *(const v4h*)&Ub[p * 20 + quad * 4];
                acc[jj] = __builtin_amdgcn_mfma_f32_16x16x16f16(a, bv, acc[jj], 0, 0, 0);
            }
        }
        if (ci < 3) stage(ci + 1);
    }

    // ---- epilogue: out = acc + vb2 + vw0*x ----
    {
        float vb2r[4], vw0[4];
        #pragma unroll
        for (int r = 0; r < 4; ++r) {
            const int e = mt * 16 + quad * 4 + r;
            vb2r[r] = stats[VB2_OFF + e];
            vw0[r]  = vw[e * 32];
        }
        #pragma unroll
        for (int jj = 0; jj < 8; ++jj) {
            const int p = (jbase + jj) * 16 + m15;
            const int py = p >> 4, px = p & 15;
            const int ogy = ty0 + py, ogx = tx0 + px;
            const float xv = x[(size_t)b * HWSZ + (size_t)ogy * WW + ogx];
            const size_t obase = (size_t)b * 32 * HWSZ + (size_t)ogy * WW + ogx;
            #pragma unroll
            for (int r = 0; r < 4; ++r) {
                const int e = mt * 16 + quad * 4 + r;
                out[obase + (size_t)e * HWSZ] = acc[jj][r] + vb2r[r] + vw0[r] * xv;
            }
        }
    }
}

// ---------------------------------------------------------------------------
extern "C" void kernel_launch(void* const* d_in, const int* in_sizes, int n_in,
                              void* d_out, int out_size, void* d_ws, size_t ws_size,
                              hipStream_t stream)
{
    (void)in_sizes; (void)n_in; (void)out_size; (void)ws_size;

    const float* x    = (const float*)d_in[0];
    const float* z    = (const float*)d_in[1];
    const float* nx_b = (const float*)d_in[3];
    const float* nz_w = (const float*)d_in[4];
    const float* nz_b = (const float*)d_in[5];
    const float* t1w  = (const float*)d_in[6];
    const float* t1b  = (const float*)d_in[7];
    const float* t2w  = (const float*)d_in[8];
    const float* t2b  = (const float*)d_in[9];
    const float* p1w  = (const float*)d_in[10];
    const float* p1b  = (const float*)d_in[11];
    const float* p2w  = (const float*)d_in[12];
    const float* p2b  = (const float*)d_in[13];
    const float* g1w  = (const float*)d_in[14];
    const float* g1b  = (const float*)d_in[15];
    const float* g2w  = (const float*)d_in[16];
    const float* g2b  = (const float*)d_in[17];
    const float* ww   = (const float*)d_in[18];
    const float* wb   = (const float*)d_in[19];
    const float* vw   = (const float*)d_in[20];
    const float* vb   = (const float*)d_in[21];
    const float* pe1w = (const float*)d_in[22];
    const float* pe2w = (const float*)d_in[23];

    __half* z2   = (__half*)d_ws;
    float* stats = (float*)((char*)d_ws + Z2F * sizeof(__half));

    hipMemsetAsync(stats, 0, 1240 * sizeof(float), stream);

    dim3 grid(WW / 16, HH / 16, BN);
    dim3 blk(256);

    blockNL_k_stage1<<<grid, blk, 0, stream>>>(z, nz_w, nz_b, t1w, t1b, t2w, t2b,
                                               g1w, g1b, g2w, g2b, z2, stats);
    blockNL_k_att<<<4, 64, 0, stream>>>(nx_b, p1w, p1b, p2w, p2b, ww, wb, vw, vb,
                                        stats);
    blockNL_k_out<<<grid, blk, 0, stream>>>(x, z, vw, pe1w, pe2w, z2, stats,
                                            (float*)d_out);
}